// Round 18
// baseline (431.002 us; speedup 1.0000x reference)
//
#include <hip/hip_runtime.h>
#include <cstdint>
#include <cstddef>

#define S_ 2048
#define D_ 64

typedef __attribute__((ext_vector_type(4))) float f32x4;
typedef __attribute__((ext_vector_type(4))) int i32x4;
typedef __attribute__((ext_vector_type(8))) __bf16 bf16x8;
typedef __attribute__((ext_vector_type(8))) unsigned short us8;
typedef __attribute__((ext_vector_type(4))) unsigned short us4;

static __device__ __forceinline__ unsigned short f2bf(float f) {
  unsigned int u = __builtin_bit_cast(unsigned int, f);
  u += 0x7fffu + ((u >> 16) & 1u);          // RNE (no NaNs in this problem)
  return (unsigned short)(u >> 16);
}
static __device__ __forceinline__ float bf2f(unsigned short h) {
  unsigned int u = ((unsigned int)h) << 16;
  return __builtin_bit_cast(float, u);
}
static __device__ __forceinline__ bf16x8 cvt8(const float* p) {
  f32x4 a = *(const f32x4*)p;
  f32x4 b = *(const f32x4*)(p + 4);
  us8 t;
  t[0]=f2bf(a[0]); t[1]=f2bf(a[1]); t[2]=f2bf(a[2]); t[3]=f2bf(a[3]);
  t[4]=f2bf(b[0]); t[5]=f2bf(b[1]); t[6]=f2bf(b[2]); t[7]=f2bf(b[3]);
  return __builtin_bit_cast(bf16x8, t);
}

// ---------- prekernel 1: f32 -> bf16 elementwise (Q, K) ----------
__global__ __launch_bounds__(256)
void cvt_bf16_kernel(const float* __restrict__ src, unsigned short* __restrict__ dst, int n4) {
  int i = blockIdx.x * 256 + threadIdx.x;
  int stride = gridDim.x * 256;
  for (; i < n4; i += stride) {
    f32x4 v = ((const f32x4*)src)[i];
    us4 o; o[0]=f2bf(v[0]); o[1]=f2bf(v[1]); o[2]=f2bf(v[2]); o[3]=f2bf(v[3]);
    ((us4*)dst)[i] = o;
  }
}

// ---------- prekernel 2: V [bh][s][d] f32 -> Vt [bh][d][s] bf16 ----------
__global__ __launch_bounds__(256)
void vtrans_kernel(const float* __restrict__ V, unsigned short* __restrict__ Vt) {
  __shared__ unsigned short T[64][72];
  const int bh = blockIdx.x >> 5;
  const int s0 = (blockIdx.x & 31) * 64;
  const int tid = threadIdx.x;
#pragma unroll
  for (int it = 0; it < 4; ++it) {
    int idx = it * 256 + tid;
    int s = idx >> 4, d4 = (idx & 15) * 4;
    f32x4 v = *(const f32x4*)&V[((size_t)bh * S_ + s0 + s) * D_ + d4];
    T[s][d4+0] = f2bf(v[0]); T[s][d4+1] = f2bf(v[1]);
    T[s][d4+2] = f2bf(v[2]); T[s][d4+3] = f2bf(v[3]);
  }
  __syncthreads();
#pragma unroll
  for (int it = 0; it < 2; ++it) {
    int idx = it * 256 + tid;
    int d = idx >> 3, s8 = (idx & 7) * 8;
    us8 w;
#pragma unroll
    for (int j = 0; j < 8; ++j) w[j] = T[s8 + j][d];
    *(us8*)&Vt[((size_t)bh * D_ + d) * S_ + s0 + s8] = w;
  }
}

// ---------- main fused attention: Qtile=128, swapped QK^T, one K-load feeds 16
// MFMAs, wide NT P stores, barrier-free pass 2 ----------
template<int PRE>
__global__ __launch_bounds__(256, 2)
void attn_kernel(const float* __restrict__ Q, const float* __restrict__ K,
                 const float* __restrict__ V, const int* __restrict__ M,
                 const unsigned short* __restrict__ Qb,
                 const unsigned short* __restrict__ Kb,
                 const unsigned short* __restrict__ Vt,
                 float* __restrict__ outO, float* __restrict__ outP)
{
  // wave-private P stash [wave][128 q][64 k + 8 pad] bf16 (73.7 KB);
  // aliased as f32 O-reduce scratch [wave][32 q][64 d] (32 KB) in epilogue.
  __shared__ __align__(16) unsigned short sP[4][128][72];
  __shared__ float sRed[4][128];
  __shared__ float sSum[128];

  const int tid  = threadIdx.x;
  const int wid  = tid >> 6;      // 0..3, owns k-slice [wid*512, wid*512+512)
  const int lane = tid & 63;
  const int l15  = lane & 15;
  const int l4   = lane >> 4;
  const int kbase = wid * 512;

  // XCD swizzle: 1024 blocks = 8 * 128 (bijective); heads grouped per XCD.
  const int bid = ((blockIdx.x & 7) << 7) | (blockIdx.x >> 3);
  const int bh = bid >> 4;     // 0..63
  const int qt = bid & 15;     // 128-row Q tile
  const int b  = bh >> 4;

  const float* Qh = Q + ((size_t)bh * S_ + (size_t)qt * 128) * D_;
  const float* Kh = K + (size_t)bh * S_ * D_;
  const float* Vh = V + (size_t)bh * S_ * D_;
  const int*   Mb = M + (size_t)b * S_;
  float* Ph = outP + (size_t)bh * S_ * S_ + (size_t)qt * 128 * S_;
  float* Oh = outO + ((size_t)bh * S_ + (size_t)qt * 128) * D_;

  // Q fragments (B-operand of swapped QK^T): rt covers rows rt*16+l15
  bf16x8 qa[8][2];
#pragma unroll
  for (int rt = 0; rt < 8; ++rt)
#pragma unroll
    for (int sk = 0; sk < 2; ++sk) {
      if (PRE)
        qa[rt][sk] = __builtin_bit_cast(bf16x8,
          *(const us8*)&Qb[((size_t)(bh * S_ + qt*128 + rt*16 + l15)) * D_ + sk*32 + l4*8]);
      else
        qa[rt][sk] = cvt8(Qh + (rt*16 + l15) * D_ + sk*32 + l4*8);
    }

  // ---------- pass 1: row exp-sums; ONE K-load feeds 8 row-tiles (16 MFMAs) ----------
  float rs[8] = {0.f,0.f,0.f,0.f,0.f,0.f,0.f,0.f};
  for (int i = 0; i < 32; ++i) {
    const int col0 = kbase + i*16;
    const i32x4 mk4 = *(const i32x4*)&Mb[col0 + l4*4];
    bf16x8 kf0, kf1;
    if (PRE) {
      const unsigned short* kp = &Kb[(size_t)(bh * S_ + col0 + l15) * D_ + l4*8];
      kf0 = __builtin_bit_cast(bf16x8, *(const us8*)kp);
      kf1 = __builtin_bit_cast(bf16x8, *(const us8*)(kp + 32));
    } else {
      const float* kp = Kh + (size_t)(col0 + l15) * D_ + l4*8;
      kf0 = cvt8(kp); kf1 = cvt8(kp + 32);
    }
#pragma unroll
    for (int rt = 0; rt < 8; ++rt) {
      f32x4 acc = {0.f,0.f,0.f,0.f};
      acc = __builtin_amdgcn_mfma_f32_16x16x32_bf16(kf0, qa[rt][0], acc, 0,0,0);
      acc = __builtin_amdgcn_mfma_f32_16x16x32_bf16(kf1, qa[rt][1], acc, 0,0,0);
      // lane holds S[k=col0+l4*4+r][q=rt*16+l15]
#pragma unroll
      for (int r = 0; r < 4; ++r)
        rs[rt] += mk4[r] ? __expf(acc[r] * 0.125f) : 0.f;
    }
  }
#pragma unroll
  for (int rt = 0; rt < 8; ++rt) {
    rs[rt] += __shfl_xor(rs[rt], 16);
    rs[rt] += __shfl_xor(rs[rt], 32);
  }
  if (l4 == 0) {
#pragma unroll
    for (int rt = 0; rt < 8; ++rt)
      sRed[wid][rt*16 + l15] = rs[rt];
  }
  __syncthreads();
  if (tid < 128) {
    float t = sRed[0][tid] + sRed[1][tid] + sRed[2][tid] + sRed[3][tid];
    sSum[tid] = 1.0f / t;
  }
  __syncthreads();
  float rvq[8];
#pragma unroll
  for (int rt = 0; rt < 8; ++rt) rvq[rt] = sSum[rt*16 + l15];

  // ---------- pass 2: BARRIER-FREE. recompute (swapped), wide NT stores, PV ----------
  f32x4 oacc[8][4];
#pragma unroll
  for (int rt = 0; rt < 8; ++rt)
#pragma unroll
    for (int dt = 0; dt < 4; ++dt)
      oacc[rt][dt] = (f32x4){0.f,0.f,0.f,0.f};

  const unsigned short* VtW = PRE ? &Vt[(size_t)bh * D_ * S_] : nullptr;

  for (int g = 0; g < 8; ++g) {
    const int c0 = kbase + g*64;
#pragma unroll
    for (int ct = 0; ct < 4; ++ct) {
      const int col0 = c0 + ct*16;
      const i32x4 mk4 = *(const i32x4*)&Mb[col0 + l4*4];
      bf16x8 kf0, kf1;
      if (PRE) {
        const unsigned short* kp = &Kb[(size_t)(bh * S_ + col0 + l15) * D_ + l4*8];
        kf0 = __builtin_bit_cast(bf16x8, *(const us8*)kp);
        kf1 = __builtin_bit_cast(bf16x8, *(const us8*)(kp + 32));
      } else {
        const float* kp = Kh + (size_t)(col0 + l15) * D_ + l4*8;
        kf0 = cvt8(kp); kf1 = cvt8(kp + 32);
      }
#pragma unroll
      for (int rt = 0; rt < 8; ++rt) {
        f32x4 a = {0.f,0.f,0.f,0.f};
        a = __builtin_amdgcn_mfma_f32_16x16x32_bf16(kf0, qa[rt][0], a, 0,0,0);
        a = __builtin_amdgcn_mfma_f32_16x16x32_bf16(kf1, qa[rt][1], a, 0,0,0);
        // lane holds S[k=col0+l4*4+r][q=rt*16+l15]: 4 consecutive k of one q-row
        f32x4 pw; us4 pb;
#pragma unroll
        for (int r = 0; r < 4; ++r) {
          float p = mk4[r] ? __expf(a[r] * 0.125f) * rvq[rt] : 0.f;
          pw[r] = p; pb[r] = f2bf(p);
        }
        __builtin_nontemporal_store(pw,
          (f32x4*)&Ph[(size_t)(rt*16 + l15) * S_ + col0 + l4*4]);   // 16B/lane NT store
        *(us4*)&sP[wid][rt*16 + l15][ct*16 + l4*4] = pb;            // 8B ds_write
      }
    }
    // PV on this wave's own stash; partial O over all 64 d, 8 row-tiles
#pragma unroll
    for (int kb = 0; kb < 2; ++kb) {
#pragma unroll
      for (int dt = 0; dt < 4; ++dt) {
        us8 vb;
        if (PRE) {
          vb = *(const us8*)&VtW[(size_t)(dt*16 + l15) * S_ + c0 + kb*32 + l4*8];
        } else {
#pragma unroll
          for (int j = 0; j < 8; ++j)
            vb[j] = f2bf(Vh[(size_t)(c0 + kb*32 + l4*8 + j) * D_ + dt*16 + l15]);
        }
#pragma unroll
        for (int rt = 0; rt < 8; ++rt) {
          bf16x8 pa = __builtin_bit_cast(bf16x8,
            *(const us8*)&sP[wid][rt*16 + l15][kb*32 + l4*8]);
          oacc[rt][dt] = __builtin_amdgcn_mfma_f32_16x16x32_bf16(
                             pa, __builtin_bit_cast(bf16x8, vb), oacc[rt][dt], 0,0,0);
        }
      }
    }
  }

  // ---------- epilogue: cross-wave O reduction (4 chunks of 32 rows) ----------
  float* sO = (float*)&sP[0][0][0];   // [4][32][64] f32 (32 KB) aliases sP (73.7 KB)
#pragma unroll
  for (int c = 0; c < 4; ++c) {
    __syncthreads();   // stash reads done / previous chunk reads done
#pragma unroll
    for (int rh = 0; rh < 2; ++rh) {          // rt = c*2 + rh
      const int rt = c*2 + rh;
#pragma unroll
      for (int dt = 0; dt < 4; ++dt)
#pragma unroll
        for (int r = 0; r < 4; ++r)
          sO[wid*2048 + (rh*16 + l4*4 + r)*64 + dt*16 + l15] = oacc[rt][dt][r];
    }
    __syncthreads();
#pragma unroll
    for (int jj = 0; jj < 2; ++jj) {
      const int t = jj*256 + tid;             // 512 tasks: 32 rows x 16 d-quads
      const int row = t >> 4;
      const int d0  = (t & 15) * 4;
      f32x4 s = *(const f32x4*)&sO[row*64 + d0];
      s += *(const f32x4*)&sO[2048 + row*64 + d0];
      s += *(const f32x4*)&sO[4096 + row*64 + d0];
      s += *(const f32x4*)&sO[6144 + row*64 + d0];
      __builtin_nontemporal_store(s, (f32x4*)&Oh[(size_t)(c*32 + row) * D_ + d0]);
    }
  }
}

extern "C" void kernel_launch(void* const* d_in, const int* in_sizes, int n_in,
                              void* d_out, int out_size, void* d_ws, size_t ws_size,
                              hipStream_t stream) {
  const float* Q = (const float*)d_in[0];
  const float* K = (const float*)d_in[1];
  const float* V = (const float*)d_in[2];
  const int*   M = (const int*)d_in[3];
  float* outO = (float*)d_out;                                  // (B,H,S,D)
  float* outP = (float*)d_out + (size_t)4 * 16 * 2048 * 64;     // (B,H,S,S)

  const size_t bytesEach = (size_t)64 * 2048 * 64 * 2;          // 16 MiB per bf16 array
  const size_t need = 3 * bytesEach;

  if (ws_size >= need) {
    unsigned short* Vt = (unsigned short*)d_ws;
    unsigned short* Kb = (unsigned short*)((char*)d_ws + bytesEach);
    unsigned short* Qb = (unsigned short*)((char*)d_ws + 2 * bytesEach);
    const int n4 = 64 * 2048 * 64 / 4;
    cvt_bf16_kernel<<<dim3(2048), dim3(256), 0, stream>>>(K, Kb, n4);
    cvt_bf16_kernel<<<dim3(2048), dim3(256), 0, stream>>>(Q, Qb, n4);
    vtrans_kernel<<<dim3(2048), dim3(256), 0, stream>>>(V, Vt);
    attn_kernel<1><<<dim3(1024), dim3(256), 0, stream>>>(Q, K, V, M, Qb, Kb, Vt, outO, outP);
  } else {
    attn_kernel<0><<<dim3(1024), dim3(256), 0, stream>>>(Q, K, V, M,
        (const unsigned short*)nullptr, (const unsigned short*)nullptr,
        (const unsigned short*)nullptr, outO, outP);
  }
}

// Round 19
// 350.497 us; speedup vs baseline: 1.2297x; 1.2297x over previous
//
#include <hip/hip_runtime.h>
#include <cstdint>
#include <cstddef>

#define S_ 2048
#define D_ 64

typedef __attribute__((ext_vector_type(4))) float f32x4;
typedef __attribute__((ext_vector_type(4))) int i32x4;
typedef __attribute__((ext_vector_type(8))) __bf16 bf16x8;
typedef __attribute__((ext_vector_type(8))) unsigned short us8;
typedef __attribute__((ext_vector_type(4))) unsigned short us4;

static __device__ __forceinline__ unsigned short f2bf(float f) {
  unsigned int u = __builtin_bit_cast(unsigned int, f);
  u += 0x7fffu + ((u >> 16) & 1u);          // RNE (no NaNs in this problem)
  return (unsigned short)(u >> 16);
}
static __device__ __forceinline__ float bf2f(unsigned short h) {
  unsigned int u = ((unsigned int)h) << 16;
  return __builtin_bit_cast(float, u);
}
static __device__ __forceinline__ bf16x8 cvt8(const float* p) {
  f32x4 a = *(const f32x4*)p;
  f32x4 b = *(const f32x4*)(p + 4);
  us8 t;
  t[0]=f2bf(a[0]); t[1]=f2bf(a[1]); t[2]=f2bf(a[2]); t[3]=f2bf(a[3]);
  t[4]=f2bf(b[0]); t[5]=f2bf(b[1]); t[6]=f2bf(b[2]); t[7]=f2bf(b[3]);
  return __builtin_bit_cast(bf16x8, t);
}

// ---------- prekernel 1: f32 -> bf16 elementwise (Q, K) ----------
__global__ __launch_bounds__(256)
void cvt_bf16_kernel(const float* __restrict__ src, unsigned short* __restrict__ dst, int n4) {
  int i = blockIdx.x * 256 + threadIdx.x;
  int stride = gridDim.x * 256;
  for (; i < n4; i += stride) {
    f32x4 v = ((const f32x4*)src)[i];
    us4 o; o[0]=f2bf(v[0]); o[1]=f2bf(v[1]); o[2]=f2bf(v[2]); o[3]=f2bf(v[3]);
    ((us4*)dst)[i] = o;
  }
}

// ---------- prekernel 2: V [bh][s][d] f32 -> Vt [bh][d][s] bf16 ----------
__global__ __launch_bounds__(256)
void vtrans_kernel(const float* __restrict__ V, unsigned short* __restrict__ Vt) {
  __shared__ unsigned short T[64][72];
  const int bh = blockIdx.x >> 5;
  const int s0 = (blockIdx.x & 31) * 64;
  const int tid = threadIdx.x;
#pragma unroll
  for (int it = 0; it < 4; ++it) {
    int idx = it * 256 + tid;
    int s = idx >> 4, d4 = (idx & 15) * 4;
    f32x4 v = *(const f32x4*)&V[((size_t)bh * S_ + s0 + s) * D_ + d4];
    T[s][d4+0] = f2bf(v[0]); T[s][d4+1] = f2bf(v[1]);
    T[s][d4+2] = f2bf(v[2]); T[s][d4+3] = f2bf(v[3]);
  }
  __syncthreads();
#pragma unroll
  for (int it = 0; it < 2; ++it) {
    int idx = it * 256 + tid;
    int d = idx >> 3, s8 = (idx & 7) * 8;
    us8 w;
#pragma unroll
    for (int j = 0; j < 8; ++j) w[j] = T[s8 + j][d];
    *(us8*)&Vt[((size_t)bh * D_ + d) * S_ + s0 + s8] = w;
  }
}

// ---------- main fused attention: Qtile=64, swapped QK^T, LINE-PAIRED NT stores
// (same-128B-line segments issued back-to-back), barrier-free pass 2 ----------
template<int PRE>
__global__ __launch_bounds__(256, 3)
void attn_kernel(const float* __restrict__ Q, const float* __restrict__ K,
                 const float* __restrict__ V, const int* __restrict__ M,
                 const unsigned short* __restrict__ Qb,
                 const unsigned short* __restrict__ Kb,
                 const unsigned short* __restrict__ Vt,
                 float* __restrict__ outO, float* __restrict__ outP)
{
  // wave-private P stash [wave][64 q][64 k + 8 pad] bf16 (36.9 KB);
  // aliased as f32 O-reduce scratch [wave][32 q][64 d] (32 KB) in epilogue.
  __shared__ __align__(16) unsigned short sP[4][64][72];
  __shared__ float sRed[4][64];
  __shared__ float sSum[64];

  const int tid  = threadIdx.x;
  const int wid  = tid >> 6;      // 0..3, owns k-slice [wid*512, wid*512+512)
  const int lane = tid & 63;
  const int l15  = lane & 15;
  const int l4   = lane >> 4;
  const int kbase = wid * 512;

  // XCD swizzle: 2048 blocks = 8 * 256 (bijective); heads grouped per XCD.
  const int bid = ((blockIdx.x & 7) << 8) | (blockIdx.x >> 3);
  const int bh = bid >> 5;     // 0..63
  const int qt = bid & 31;     // 64-row Q tile
  const int b  = bh >> 4;

  const float* Qh = Q + ((size_t)bh * S_ + (size_t)qt * 64) * D_;
  const float* Kh = K + (size_t)bh * S_ * D_;
  const float* Vh = V + (size_t)bh * S_ * D_;
  const int*   Mb = M + (size_t)b * S_;
  float* Ph = outP + (size_t)bh * S_ * S_ + (size_t)qt * 64 * S_;
  float* Oh = outO + ((size_t)bh * S_ + (size_t)qt * 64) * D_;

  // Q fragments (B-operand of swapped QK^T): rt covers rows rt*16+l15
  bf16x8 qa[4][2];
#pragma unroll
  for (int rt = 0; rt < 4; ++rt)
#pragma unroll
    for (int sk = 0; sk < 2; ++sk) {
      if (PRE)
        qa[rt][sk] = __builtin_bit_cast(bf16x8,
          *(const us8*)&Qb[((size_t)(bh * S_ + qt*64 + rt*16 + l15)) * D_ + sk*32 + l4*8]);
      else
        qa[rt][sk] = cvt8(Qh + (rt*16 + l15) * D_ + sk*32 + l4*8);
    }

  // ---------- pass 1: row exp-sums; ONE K-load feeds 4 row-tiles (8 MFMAs) ----------
  float rs[4] = {0.f, 0.f, 0.f, 0.f};
  for (int i = 0; i < 32; ++i) {
    const int col0 = kbase + i*16;
    const i32x4 mk4 = *(const i32x4*)&Mb[col0 + l4*4];
    bf16x8 kf0, kf1;
    if (PRE) {
      const unsigned short* kp = &Kb[(size_t)(bh * S_ + col0 + l15) * D_ + l4*8];
      kf0 = __builtin_bit_cast(bf16x8, *(const us8*)kp);
      kf1 = __builtin_bit_cast(bf16x8, *(const us8*)(kp + 32));
    } else {
      const float* kp = Kh + (size_t)(col0 + l15) * D_ + l4*8;
      kf0 = cvt8(kp); kf1 = cvt8(kp + 32);
    }
#pragma unroll
    for (int rt = 0; rt < 4; ++rt) {
      f32x4 acc = {0.f,0.f,0.f,0.f};
      acc = __builtin_amdgcn_mfma_f32_16x16x32_bf16(kf0, qa[rt][0], acc, 0,0,0);
      acc = __builtin_amdgcn_mfma_f32_16x16x32_bf16(kf1, qa[rt][1], acc, 0,0,0);
      // lane holds S[k=col0+l4*4+r][q=rt*16+l15]
#pragma unroll
      for (int r = 0; r < 4; ++r)
        rs[rt] += mk4[r] ? __expf(acc[r] * 0.125f) : 0.f;
    }
  }
#pragma unroll
  for (int rt = 0; rt < 4; ++rt) {
    rs[rt] += __shfl_xor(rs[rt], 16);
    rs[rt] += __shfl_xor(rs[rt], 32);
  }
  if (l4 == 0) {
#pragma unroll
    for (int rt = 0; rt < 4; ++rt)
      sRed[wid][rt*16 + l15] = rs[rt];
  }
  __syncthreads();
  if (tid < 64) {
    float t = sRed[0][tid] + sRed[1][tid] + sRed[2][tid] + sRed[3][tid];
    sSum[tid] = 1.0f / t;
  }
  __syncthreads();
  float rvq[4];
#pragma unroll
  for (int rt = 0; rt < 4; ++rt) rvq[rt] = sSum[rt*16 + l15];

  // ---------- pass 2: BARRIER-FREE. recompute (swapped), LINE-PAIRED NT stores, PV ----------
  f32x4 oacc[4][4];
#pragma unroll
  for (int rt = 0; rt < 4; ++rt)
#pragma unroll
    for (int dt = 0; dt < 4; ++dt)
      oacc[rt][dt] = (f32x4){0.f,0.f,0.f,0.f};

  const unsigned short* VtW = PRE ? &Vt[(size_t)bh * D_ * S_] : nullptr;

  for (int g = 0; g < 8; ++g) {
    const int c0 = kbase + g*64;
    // batched K/mask loads for all 4 sub-tiles of this group
    i32x4 mk4[4]; bf16x8 kf[4][2];
#pragma unroll
    for (int ct = 0; ct < 4; ++ct) {
      const int col0 = c0 + ct*16;
      mk4[ct] = *(const i32x4*)&Mb[col0 + l4*4];
      if (PRE) {
        const unsigned short* kp = &Kb[(size_t)(bh * S_ + col0 + l15) * D_ + l4*8];
        kf[ct][0] = __builtin_bit_cast(bf16x8, *(const us8*)kp);
        kf[ct][1] = __builtin_bit_cast(bf16x8, *(const us8*)(kp + 32));
      } else {
        const float* kp = Kh + (size_t)(col0 + l15) * D_ + l4*8;
        kf[ct][0] = cvt8(kp); kf[ct][1] = cvt8(kp + 32);
      }
    }
    // per row-tile: compute ALL 4 ct fragments, then issue the 4 NT stores
    // back-to-back (ct0+ct1 tile one 128B line, ct2+ct3 the next)
#pragma unroll
    for (int rt = 0; rt < 4; ++rt) {
      f32x4 pw[4]; us4 pb[4];
#pragma unroll
      for (int ct = 0; ct < 4; ++ct) {
        f32x4 a = {0.f,0.f,0.f,0.f};
        a = __builtin_amdgcn_mfma_f32_16x16x32_bf16(kf[ct][0], qa[rt][0], a, 0,0,0);
        a = __builtin_amdgcn_mfma_f32_16x16x32_bf16(kf[ct][1], qa[rt][1], a, 0,0,0);
#pragma unroll
        for (int r = 0; r < 4; ++r) {
          float p = mk4[ct][r] ? __expf(a[r] * 0.125f) * rvq[rt] : 0.f;
          pw[ct][r] = p; pb[ct][r] = f2bf(p);
        }
      }
      float* prow = &Ph[(size_t)(rt*16 + l15) * S_ + c0 + l4*4];
#pragma unroll
      for (int ct = 0; ct < 4; ++ct)
        __builtin_nontemporal_store(pw[ct], (f32x4*)(prow + ct*16));
#pragma unroll
      for (int ct = 0; ct < 4; ++ct)
        *(us4*)&sP[wid][rt*16 + l15][ct*16 + l4*4] = pb[ct];
    }
    // PV on this wave's own stash; partial O over all 64 d, 4 row-tiles
#pragma unroll
    for (int kb = 0; kb < 2; ++kb) {
      bf16x8 pa[4];
#pragma unroll
      for (int rt = 0; rt < 4; ++rt)
        pa[rt] = __builtin_bit_cast(bf16x8,
          *(const us8*)&sP[wid][rt*16 + l15][kb*32 + l4*8]);
#pragma unroll
      for (int dt = 0; dt < 4; ++dt) {
        us8 vb;
        if (PRE) {
          vb = *(const us8*)&VtW[(size_t)(dt*16 + l15) * S_ + c0 + kb*32 + l4*8];
        } else {
#pragma unroll
          for (int j = 0; j < 8; ++j)
            vb[j] = f2bf(Vh[(size_t)(c0 + kb*32 + l4*8 + j) * D_ + dt*16 + l15]);
        }
#pragma unroll
        for (int rt = 0; rt < 4; ++rt)
          oacc[rt][dt] = __builtin_amdgcn_mfma_f32_16x16x32_bf16(
                             pa[rt], __builtin_bit_cast(bf16x8, vb), oacc[rt][dt], 0,0,0);
      }
    }
  }

  // ---------- epilogue: cross-wave O reduction (2 chunks of 32 rows) ----------
  float* sO = (float*)&sP[0][0][0];   // [4][32][64] f32 (32 KB) aliases sP (36.9 KB)
#pragma unroll
  for (int rt2 = 0; rt2 < 2; ++rt2) {
    __syncthreads();   // stash reads done / previous chunk reads done
#pragma unroll
    for (int rh = 0; rh < 2; ++rh) {          // rt = rt2*2 + rh
      const int rt = rt2*2 + rh;
#pragma unroll
      for (int dt = 0; dt < 4; ++dt)
#pragma unroll
        for (int r = 0; r < 4; ++r)
          sO[wid*2048 + (rh*16 + l4*4 + r)*64 + dt*16 + l15] = oacc[rt][dt][r];
    }
    __syncthreads();
#pragma unroll
    for (int jj = 0; jj < 2; ++jj) {
      const int t = jj*256 + tid;             // 512 tasks: 32 rows x 16 d-quads
      const int row = t >> 4;
      const int d0  = (t & 15) * 4;
      f32x4 s = *(const f32x4*)&sO[row*64 + d0];
      s += *(const f32x4*)&sO[2048 + row*64 + d0];
      s += *(const f32x4*)&sO[4096 + row*64 + d0];
      s += *(const f32x4*)&sO[6144 + row*64 + d0];
      __builtin_nontemporal_store(s, (f32x4*)&Oh[(size_t)(rt2*32 + row) * D_ + d0]);
    }
  }
}

extern "C" void kernel_launch(void* const* d_in, const int* in_sizes, int n_in,
                              void* d_out, int out_size, void* d_ws, size_t ws_size,
                              hipStream_t stream) {
  const float* Q = (const float*)d_in[0];
  const float* K = (const float*)d_in[1];
  const float* V = (const float*)d_in[2];
  const int*   M = (const int*)d_in[3];
  float* outO = (float*)d_out;                                  // (B,H,S,D)
  float* outP = (float*)d_out + (size_t)4 * 16 * 2048 * 64;     // (B,H,S,S)

  const size_t bytesEach = (size_t)64 * 2048 * 64 * 2;          // 16 MiB per bf16 array
  const size_t need = 3 * bytesEach;

  if (ws_size >= need) {
    unsigned short* Vt = (unsigned short*)d_ws;
    unsigned short* Kb = (unsigned short*)((char*)d_ws + bytesEach);
    unsigned short* Qb = (unsigned short*)((char*)d_ws + 2 * bytesEach);
    const int n4 = 64 * 2048 * 64 / 4;
    cvt_bf16_kernel<<<dim3(2048), dim3(256), 0, stream>>>(K, Kb, n4);
    cvt_bf16_kernel<<<dim3(2048), dim3(256), 0, stream>>>(Q, Qb, n4);
    vtrans_kernel<<<dim3(2048), dim3(256), 0, stream>>>(V, Vt);
    attn_kernel<1><<<dim3(2048), dim3(256), 0, stream>>>(Q, K, V, M, Qb, Kb, Vt, outO, outP);
  } else {
    attn_kernel<0><<<dim3(2048), dim3(256), 0, stream>>>(Q, K, V, M,
        (const unsigned short*)nullptr, (const unsigned short*)nullptr,
        (const unsigned short*)nullptr, outO, outP);
  }
}